// Round 10
// baseline (54.333 us; speedup 1.0000x reference)
//
#include <hip/hip_runtime.h>

#define B_ 2
#define N_ 16384
#define M_ 8192
#define CH 8                      // scan chunks per block (8*256 = 2048 cols)

typedef float f32x4 __attribute__((ext_vector_type(4)));
typedef short s16x8 __attribute__((ext_vector_type(8)));

__device__ inline float min3f(float a, float b, float c) {
    float d;
    asm("v_min3_f32 %0, %1, %2, %3" : "=v"(d) : "v"(a), "v"(b), "v"(c));
    return d;
}

// RNE f32 -> bf16 (bits)
__device__ inline unsigned short f2bf(float f) {
    unsigned int u = __float_as_uint(f);
    u += 0x7FFFu + ((u >> 16) & 1u);
    return (unsigned short)(u >> 16);
}
__device__ inline float bf2f(unsigned short h) {
    return __uint_as_float(((unsigned int)h) << 16);
}
// 3-way bf16 split: v ~= h + m + l to ~2^-24 rel
__device__ inline void split3(float v, unsigned short& hb, unsigned short& mb,
                              unsigned short& lb) {
    hb = f2bf(v);
    float r1 = v - bf2f(hb);
    mb = f2bf(r1);
    float r2 = r1 - bf2f(mb);
    lb = f2bf(r2);
}

#define ONE_BF ((short)0x3F80)

// fragment builders — verbatim slot maps from the verified rounds 4/6/8/9
// kernels. A-form carries u=-2p (and ||p||^2 at slots 18-20); B-form carries
// p raw (and ||p||^2 at slots 21-23). A-form(x) x B-form(y) == |x-y|^2.
// Direction swap A-form(y) x B-form(x) gives the SAME products per slot
// (bf16(-2x)*bf16(y) == bf16(x)*bf16(-2y) exactly: *2 is exponent-exact),
// only the two sq-split slot trios swap -> sum differs by <= ulp-level.
__device__ inline void buildA(float x0, float x1, float x2,
                              s16x8& g0, s16x8& g1, s16x8& g2) {
    float sq = fmaf(x0, x0, fmaf(x1, x1, x2 * x2));
    unsigned short uh[3], um[3], ul[3], s1[3];
    split3(-2.f * x0, uh[0], um[0], ul[0]);
    split3(-2.f * x1, uh[1], um[1], ul[1]);
    split3(-2.f * x2, uh[2], um[2], ul[2]);
    split3(sq, s1[0], s1[1], s1[2]);
    g0 = (s16x8){(short)uh[0], (short)uh[1], (short)uh[2], (short)uh[0],
                 (short)uh[1], (short)uh[2], (short)um[0], (short)um[1]};
    g1 = (s16x8){(short)um[2], (short)uh[0], (short)uh[1], (short)uh[2],
                 (short)ul[0], (short)ul[1], (short)ul[2], (short)um[0]};
    g2 = (s16x8){(short)um[1], (short)um[2], (short)s1[0], (short)s1[1],
                 (short)s1[2], ONE_BF, ONE_BF, ONE_BF};
}
__device__ inline void buildB(float y0, float y1, float y2,
                              s16x8& g0, s16x8& g1, s16x8& g2) {
    float sq = fmaf(y0, y0, fmaf(y1, y1, y2 * y2));
    unsigned short yh[3], ym[3], yl[3], s2[3];
    split3(y0, yh[0], ym[0], yl[0]);
    split3(y1, yh[1], ym[1], yl[1]);
    split3(y2, yh[2], ym[2], yl[2]);
    split3(sq, s2[0], s2[1], s2[2]);
    g0 = (s16x8){(short)yh[0], (short)yh[1], (short)yh[2], (short)ym[0],
                 (short)ym[1], (short)ym[2], (short)yh[0], (short)yh[1]};
    g1 = (s16x8){(short)yh[2], (short)yl[0], (short)yl[1], (short)yl[2],
                 (short)yh[0], (short)yh[1], (short)yh[2], (short)ym[0]};
    g2 = (s16x8){(short)ym[1], (short)ym[2], ONE_BF, ONE_BF, ONE_BF,
                 (short)s2[0], (short)s2[1], (short)s2[2]};
}

// ---------------- reductions ----------------

__device__ inline float blk_reduce_max(float v, float* red) {
    #pragma unroll
    for (int off = 32; off; off >>= 1) v = fmaxf(v, __shfl_xor(v, off));
    int wid = threadIdx.x >> 6;
    int lane = threadIdx.x & 63;
    int nw = blockDim.x >> 6;
    if (lane == 0) red[wid] = v;
    __syncthreads();
    if (wid == 0) {
        v = (lane < nw) ? red[lane] : -3.402823466e38f;
        #pragma unroll
        for (int off = 32; off; off >>= 1) v = fmaxf(v, __shfl_xor(v, off));
        if (lane == 0) red[0] = v;
    }
    __syncthreads();
    v = red[0];
    __syncthreads();
    return v;
}

__device__ inline float blk_reduce_sum(float v, float* red) {
    #pragma unroll
    for (int off = 32; off; off >>= 1) v += __shfl_xor(v, off);
    int wid = threadIdx.x >> 6;
    int lane = threadIdx.x & 63;
    int nw = blockDim.x >> 6;
    if (lane == 0) red[wid] = v;
    __syncthreads();
    if (wid == 0) {
        v = (lane < nw) ? red[lane] : 0.0f;
        #pragma unroll
        for (int off = 32; off; off >>= 1) v += __shfl_xor(v, off);
        if (lane == 0) red[0] = v;
    }
    __syncthreads();
    v = red[0];
    __syncthreads();
    return v;
}

// ---------------- kernels ----------------

// grid 128 blocks. Init ws + weight wave-maxes + precompute BOTH fragment
// forms for BOTH clouds (round-10: the two-direction kernel needs A-form and
// B-form of each point; built once here, ~0.8K VALU/thread, trivial).
__global__ __launch_bounds__(256) void init_ws(const float* __restrict__ wts,
                                               const float* __restrict__ p1,
                                               const float* __restrict__ p2,
                                               unsigned int* min1, unsigned int* min2,
                                               float* __restrict__ wmax_part,
                                               s16x8* __restrict__ A1f,
                                               s16x8* __restrict__ B1f,
                                               s16x8* __restrict__ A2f,
                                               s16x8* __restrict__ B2f,
                                               float* out) {
    int i = blockIdx.x * 256 + threadIdx.x;   // [0, B_*N_)
    min1[i] = 0x7F7FFFFFu;                    // FLT_MAX bits
    if (i < B_ * M_) min2[i] = 0x7F7FFFFFu;
    if (i == 0) out[0] = 0.0f;

    float v = wts[i];
    #pragma unroll
    for (int off = 32; off; off >>= 1) v = fmaxf(v, __shfl_xor(v, off));
    if ((threadIdx.x & 63) == 0)
        wmax_part[blockIdx.x * 4 + (threadIdx.x >> 6)] = v;  // 4 waves/block

    // p1 point i: A-form (dir1 owner) + B-form (dir2 scanned)
    {
        int b = i >> 14, n = i & (N_ - 1);
        const float* px = p1 + (size_t)i * 3;
        float x0 = px[0], x1 = px[1], x2 = px[2];
        s16x8 g0, g1, g2;
        buildA(x0, x1, x2, g0, g1, g2);
        A1f[(b * 3 + 0) * N_ + n] = g0;
        A1f[(b * 3 + 1) * N_ + n] = g1;
        A1f[(b * 3 + 2) * N_ + n] = g2;
        buildB(x0, x1, x2, g0, g1, g2);
        B1f[(b * 3 + 0) * N_ + n] = g0;
        B1f[(b * 3 + 1) * N_ + n] = g1;
        B1f[(b * 3 + 2) * N_ + n] = g2;
    }
    // p2 point i: B-form (dir1 scanned) + A-form (dir2 owner)
    if (i < B_ * M_) {
        int b = i >> 13, m = i & (M_ - 1);
        const float* py = p2 + (size_t)i * 3;
        float y0 = py[0], y1 = py[1], y2 = py[2];
        s16x8 g0, g1, g2;
        buildB(y0, y1, y2, g0, g1, g2);
        B2f[(b * 3 + 0) * M_ + m] = g0;
        B2f[(b * 3 + 1) * M_ + m] = g1;
        B2f[(b * 3 + 2) * M_ + m] = g2;
        buildA(y0, y1, y2, g0, g1, g2);
        A2f[(b * 3 + 0) * M_ + m] = g0;
        A2f[(b * 3 + 1) * M_ + m] = g1;
        A2f[(b * 3 + 2) * M_ + m] = g2;
    }
}

// Two-direction MFMA chamfer, ROW-MIN ONLY per block (round-10 restructure):
// round-9's min2 machinery (32 lgkm-ordered shuffles + scr + extra barrier
// phase + in-loop atomic per chunk) serialized against the Bf ds_reads.
// Here EVERY block computes only row-mins for its owner set:
//   dir1 (bid<512):  owners = p1 rows (A-form), scan p2 (B-form) -> min1
//   dir2 (bid>=512): owners = p2 rows (A-form), scan p1 (B-form) -> min2
// Each distance computed twice chip-wide (MfmaUtil was 15%, headroom), but
// per-value fold halves (4 min3 / 8 values) and the in-loop stream is pure
// {2 ds_read + 8 MFMA + 16 min3} per tile-pair. Atomics 1.3M -> 262K, all in
// the epilogue. LDS 28KB (scr deleted). Grid 512+512 = 1024 = exactly 4/CU.
__global__ __launch_bounds__(256) void chamfer_mfma(
        const s16x8* __restrict__ A1f, const s16x8* __restrict__ B1f,
        const s16x8* __restrict__ A2f, const s16x8* __restrict__ B2f,
        unsigned int* __restrict__ min1, unsigned int* __restrict__ min2) {
    __shared__ s16x8 Apl[3][256];        // 12KB
    __shared__ s16x8 Bpl[4][256];        // 16KB (plane 3 = zeros)

    const int bid = blockIdx.x;
    const s16x8* Aown;
    const s16x8* Bscan;
    unsigned int* mg;
    int nb, mbase, NA, NB;
    if (bid < 512) {                     // dir1
        int b = bid >> 8, r = bid & 255;
        nb    = (r >> 2) * 256;          // 64 owner blocks over N
        mbase = (r & 3) * (CH * 256);    // 4 bins over M
        NA = N_; NB = M_;
        Aown = A1f + (size_t)(b * 3) * N_;
        Bscan = B2f + (size_t)(b * 3) * M_;
        mg = min1 + (size_t)b * N_;
    } else {                             // dir2
        int t2 = bid - 512;
        int b = t2 >> 8, r = t2 & 255;
        nb    = (r >> 3) * 256;          // 32 owner blocks over M
        mbase = (r & 7) * (CH * 256);    // 8 bins over N
        NA = M_; NB = N_;
        Aown = A2f + (size_t)(b * 3) * M_;
        Bscan = B1f + (size_t)(b * 3) * N_;
        mg = min2 + (size_t)b * M_;
    }

    const int t = threadIdx.x;
    const int w = t >> 6, l = t & 63;
    const s16x8 zfrag = {0, 0, 0, 0, 0, 0, 0, 0};

    // ---- stage A planes + zero B plane 3 + stage B chunk 0 ----
    {
        s16x8 a0 = Aown[0 * NA + nb + t];
        s16x8 a1 = Aown[1 * NA + nb + t];
        s16x8 a2 = Aown[2 * NA + nb + t];
        s16x8 b0 = Bscan[0 * NB + mbase + t];
        s16x8 b1 = Bscan[1 * NB + mbase + t];
        s16x8 b2 = Bscan[2 * NB + mbase + t];
        Apl[0][t] = a0;
        Apl[1][t] = a1;
        Apl[2][t] = a2;
        Bpl[3][t] = zfrag;
        Bpl[0][t] = b0;
        Bpl[1][t] = b1;
        Bpl[2][t] = b2;
    }
    __syncthreads();

    s16x8 Af[4];
    #pragma unroll
    for (int r = 0; r < 4; r++)
        Af[r] = (l < 48) ? Apl[l >> 4][(4 * w + r) * 16 + (l & 15)] : zfrag;

    f32x4 mn1v[4];
    #pragma unroll
    for (int r = 0; r < 4; r++)
        mn1v[r] = (f32x4){3.402823466e38f, 3.402823466e38f,
                          3.402823466e38f, 3.402823466e38f};

    const f32x4 zacc = {0.f, 0.f, 0.f, 0.f};
    const s16x8* Bflat = &Bpl[0][0];
    const int boff = (l >> 4) * 256 + (l & 15);   // plane 3 for l>=48 -> zeros

    // ---- chunk loop: pure {ds_read, MFMA, min3} stream ----
    #pragma unroll 1
    for (int c = 0; c < CH; c++) {
        // prefetch next chunk to regs; loads land under this chunk's compute
        s16x8 pb0, pb1, pb2;
        if (c + 1 < CH) {
            int src = mbase + (c + 1) * 256 + t;
            pb0 = Bscan[0 * NB + src];
            pb1 = Bscan[1 * NB + src];
            pb2 = Bscan[2 * NB + src];
        }
        #pragma unroll 2
        for (int mp = 0; mp < 8; mp++) {
            s16x8 Bf0 = Bflat[boff + (2 * mp) * 16];
            s16x8 Bf1 = Bflat[boff + (2 * mp + 1) * 16];
            #pragma unroll
            for (int r = 0; r < 4; r++) {
                f32x4 aA = __builtin_amdgcn_mfma_f32_16x16x32_bf16(Af[r], Bf0, zacc, 0, 0, 0);
                f32x4 aB = __builtin_amdgcn_mfma_f32_16x16x32_bf16(Af[r], Bf1, zacc, 0, 0, 0);
                mn1v[r].x = min3f(mn1v[r].x, aA.x, aB.x);
                mn1v[r].y = min3f(mn1v[r].y, aA.y, aB.y);
                mn1v[r].z = min3f(mn1v[r].z, aA.z, aB.z);
                mn1v[r].w = min3f(mn1v[r].w, aA.w, aB.w);
            }
        }
        if (c + 1 < CH) {
            __syncthreads();             // all waves done reading Bpl chunk c
            Bpl[0][t] = pb0;
            Bpl[1][t] = pb1;
            Bpl[2][t] = pb2;
            __syncthreads();             // chunk c+1 staged
        }
    }

    // ---- epilogue: row-min (reduce over the 16 cols held across lanes l&15)
    #pragma unroll
    for (int r = 0; r < 4; r++) {
        #pragma unroll
        for (int q = 0; q < 4; q++) {
            float v = mn1v[r][q];
            v = fminf(v, __shfl_xor(v, 1));
            v = fminf(v, __shfl_xor(v, 2));
            v = fminf(v, __shfl_xor(v, 4));
            v = fminf(v, __shfl_xor(v, 8));
            if ((l & 15) == 0) {
                int row = nb + (4 * w + r) * 16 + (l >> 4) * 4 + q;
                // distances non-negative: float bits order as uint
                atomicMin(&mg[row], __float_as_uint(v));
            }
        }
    }
}

__global__ __launch_bounds__(1024) void finalize_kernel(
        const float* __restrict__ wts,
        const float* __restrict__ min1,
        const float* __restrict__ min2,
        const float* __restrict__ wmax_part,
        float* __restrict__ out) {
    __shared__ float red[16];
    int b = blockIdx.x;
    const float* wb = wts + b * N_;
    const float* m1 = min1 + b * N_;
    const float* m2 = min2 + b * M_;

    float lmax = (threadIdx.x < 256) ? wmax_part[b * 256 + threadIdx.x]
                                     : -3.402823466e38f;
    float gmax = blk_reduce_max(lmax, red);

    float se = 0.0f, swm = 0.0f;
    for (int i = threadIdx.x; i < N_ / 4; i += blockDim.x) {
        f32x4 w4 = ((const f32x4*)wb)[i];
        f32x4 m4 = ((const f32x4*)m1)[i];
        #pragma unroll
        for (int k = 0; k < 4; k++) {
            float e = expf(w4[k] - gmax);
            se += e;
            swm += e * m4[k];
        }
    }
    float tse = blk_reduce_sum(se, red);
    float tswm = blk_reduce_sum(swm, red);

    float sm2 = 0.0f;
    for (int i = threadIdx.x; i < M_ / 4; i += blockDim.x) {
        f32x4 m4 = ((const f32x4*)m2)[i];
        sm2 += (m4.x + m4.y) + (m4.z + m4.w);
    }
    float tsm2 = blk_reduce_sum(sm2, red);

    if (threadIdx.x == 0)
        atomicAdd(out, (tswm / tse + tsm2 * (1.0f / (float)M_)) * (1.0f / (float)B_));
}

// ---------------- launch ----------------

extern "C" void kernel_launch(void* const* d_in, const int* in_sizes, int n_in,
                              void* d_out, int out_size, void* d_ws, size_t ws_size,
                              hipStream_t stream) {
    const float* p1  = (const float*)d_in[0];  // (B, N, 3)
    const float* p2  = (const float*)d_in[1];  // (B, M, 3)
    const float* wts = (const float*)d_in[2];  // (B, N)
    float* out = (float*)d_out;

    // workspace: min1 (128KB) | min2 (64KB) | wmax (4KB pad) |
    //            A1f 1.5MB | B2f 0.75MB | A2f 0.75MB | B1f 1.5MB
    unsigned int* min1 = (unsigned int*)d_ws;            // B*N
    unsigned int* min2 = min1 + B_ * N_;                 // B*M
    float* wmax_part = (float*)(min2 + B_ * M_);         // 512 floats
    char* frag_base = (char*)d_ws + 196608 + 4096;       // 16B aligned
    s16x8* A1f = (s16x8*)frag_base;                      // B*3*N
    s16x8* B2f = A1f + B_ * 3 * N_;                      // B*3*M
    s16x8* A2f = B2f + B_ * 3 * M_;                      // B*3*M
    s16x8* B1f = A2f + B_ * 3 * M_;                      // B*3*N

    init_ws<<<dim3((B_ * N_) / 256), dim3(256), 0, stream>>>(
        wts, p1, p2, min1, min2, wmax_part, A1f, B1f, A2f, B2f, out);
    // dir1: 2b * 64ob * 4bins = 512 ; dir2: 2b * 32ob * 8bins = 512
    chamfer_mfma<<<dim3(1024), dim3(256), 0, stream>>>(
        A1f, B1f, A2f, B2f, min1, min2);
    finalize_kernel<<<dim3(B_), dim3(1024), 0, stream>>>(
        wts, (const float*)min1, (const float*)min2, wmax_part, out);
}

// Round 11
// 48.103 us; speedup vs baseline: 1.1295x; 1.1295x over previous
//
#include <hip/hip_runtime.h>

#define B_ 2
#define N_ 16384
#define M_ 8192
#define CH 2                      // scan chunks per block (2*256 = 512 cols)

typedef float f32x4 __attribute__((ext_vector_type(4)));
typedef short s16x8 __attribute__((ext_vector_type(8)));

__device__ inline float min3f(float a, float b, float c) {
    float d;
    asm("v_min3_f32 %0, %1, %2, %3" : "=v"(d) : "v"(a), "v"(b), "v"(c));
    return d;
}

// RNE f32 -> bf16 (bits)
__device__ inline unsigned short f2bf(float f) {
    unsigned int u = __float_as_uint(f);
    u += 0x7FFFu + ((u >> 16) & 1u);
    return (unsigned short)(u >> 16);
}
__device__ inline float bf2f(unsigned short h) {
    return __uint_as_float(((unsigned int)h) << 16);
}
// 3-way bf16 split: v ~= h + m + l to ~2^-24 rel
__device__ inline void split3(float v, unsigned short& hb, unsigned short& mb,
                              unsigned short& lb) {
    hb = f2bf(v);
    float r1 = v - bf2f(hb);
    mb = f2bf(r1);
    float r2 = r1 - bf2f(mb);
    lb = f2bf(r2);
}

#define ONE_BF ((short)0x3F80)

// fragment builders — verbatim slot maps from the verified rounds 4/6/8/9
__device__ inline void buildA(float x0, float x1, float x2,
                              s16x8& g0, s16x8& g1, s16x8& g2) {
    float sq = fmaf(x0, x0, fmaf(x1, x1, x2 * x2));
    unsigned short uh[3], um[3], ul[3], s1[3];
    split3(-2.f * x0, uh[0], um[0], ul[0]);
    split3(-2.f * x1, uh[1], um[1], ul[1]);
    split3(-2.f * x2, uh[2], um[2], ul[2]);
    split3(sq, s1[0], s1[1], s1[2]);
    g0 = (s16x8){(short)uh[0], (short)uh[1], (short)uh[2], (short)uh[0],
                 (short)uh[1], (short)uh[2], (short)um[0], (short)um[1]};
    g1 = (s16x8){(short)um[2], (short)uh[0], (short)uh[1], (short)uh[2],
                 (short)ul[0], (short)ul[1], (short)ul[2], (short)um[0]};
    g2 = (s16x8){(short)um[1], (short)um[2], (short)s1[0], (short)s1[1],
                 (short)s1[2], ONE_BF, ONE_BF, ONE_BF};
}
__device__ inline void buildB(float y0, float y1, float y2,
                              s16x8& g0, s16x8& g1, s16x8& g2) {
    float sq = fmaf(y0, y0, fmaf(y1, y1, y2 * y2));
    unsigned short yh[3], ym[3], yl[3], s2[3];
    split3(y0, yh[0], ym[0], yl[0]);
    split3(y1, yh[1], ym[1], yl[1]);
    split3(y2, yh[2], ym[2], yl[2]);
    split3(sq, s2[0], s2[1], s2[2]);
    g0 = (s16x8){(short)yh[0], (short)yh[1], (short)yh[2], (short)ym[0],
                 (short)ym[1], (short)ym[2], (short)yh[0], (short)yh[1]};
    g1 = (s16x8){(short)yh[2], (short)yl[0], (short)yl[1], (short)yl[2],
                 (short)yh[0], (short)yh[1], (short)yh[2], (short)ym[0]};
    g2 = (s16x8){(short)ym[1], (short)ym[2], ONE_BF, ONE_BF, ONE_BF,
                 (short)s2[0], (short)s2[1], (short)s2[2]};
}

// ---------------- reductions ----------------

__device__ inline float blk_reduce_max(float v, float* red) {
    #pragma unroll
    for (int off = 32; off; off >>= 1) v = fmaxf(v, __shfl_xor(v, off));
    int wid = threadIdx.x >> 6;
    int lane = threadIdx.x & 63;
    int nw = blockDim.x >> 6;
    if (lane == 0) red[wid] = v;
    __syncthreads();
    if (wid == 0) {
        v = (lane < nw) ? red[lane] : -3.402823466e38f;
        #pragma unroll
        for (int off = 32; off; off >>= 1) v = fmaxf(v, __shfl_xor(v, off));
        if (lane == 0) red[0] = v;
    }
    __syncthreads();
    v = red[0];
    __syncthreads();
    return v;
}

__device__ inline float blk_reduce_sum(float v, float* red) {
    #pragma unroll
    for (int off = 32; off; off >>= 1) v += __shfl_xor(v, off);
    int wid = threadIdx.x >> 6;
    int lane = threadIdx.x & 63;
    int nw = blockDim.x >> 6;
    if (lane == 0) red[wid] = v;
    __syncthreads();
    if (wid == 0) {
        v = (lane < nw) ? red[lane] : 0.0f;
        #pragma unroll
        for (int off = 32; off; off >>= 1) v += __shfl_xor(v, off);
        if (lane == 0) red[0] = v;
    }
    __syncthreads();
    v = red[0];
    __syncthreads();
    return v;
}

// ---------------- kernels ----------------

// grid 128 blocks. Init ws, weight wave-maxes, and precompute all MFMA
// fragments ONCE (round-9 proven): A-form for p1, B-form for p2.
__global__ __launch_bounds__(256) void init_ws(const float* __restrict__ wts,
                                               const float* __restrict__ p1,
                                               const float* __restrict__ p2,
                                               unsigned int* min1, unsigned int* min2,
                                               float* __restrict__ wmax_part,
                                               s16x8* __restrict__ Afrag,
                                               s16x8* __restrict__ Bfrag,
                                               float* out) {
    int i = blockIdx.x * 256 + threadIdx.x;   // [0, B_*N_)
    min1[i] = 0x7F7FFFFFu;                    // FLT_MAX bits
    if (i < B_ * M_) min2[i] = 0x7F7FFFFFu;
    if (i == 0) out[0] = 0.0f;

    float v = wts[i];
    #pragma unroll
    for (int off = 32; off; off >>= 1) v = fmaxf(v, __shfl_xor(v, off));
    if ((threadIdx.x & 63) == 0)
        wmax_part[blockIdx.x * 4 + (threadIdx.x >> 6)] = v;  // 4 waves/block

    // A fragment for p1 point i
    {
        int b = i >> 14, n = i & (N_ - 1);
        const float* px = p1 + (size_t)i * 3;
        s16x8 g0, g1, g2;
        buildA(px[0], px[1], px[2], g0, g1, g2);
        Afrag[(b * 3 + 0) * N_ + n] = g0;
        Afrag[(b * 3 + 1) * N_ + n] = g1;
        Afrag[(b * 3 + 2) * N_ + n] = g2;
    }
    // B fragment for p2 point i
    if (i < B_ * M_) {
        int b = i >> 13, m = i & (M_ - 1);
        const float* py = p2 + (size_t)i * 3;
        s16x8 g0, g1, g2;
        buildB(py[0], py[1], py[2], g0, g1, g2);
        Bfrag[(b * 3 + 0) * M_ + m] = g0;
        Bfrag[(b * 3 + 1) * M_ + m] = g1;
        Bfrag[(b * 3 + 2) * M_ + m] = g2;
    }
}

// Single-pass MFMA chamfer — ROUND-9 PROVEN STRUCTURE (best: 48.4us total),
// with ONE change for occupancy. R10's decomposition showed R9's min2
// machinery costs ~0 (hidden under latency) and R9's ~37us chamfer is
// ~6.5 MFMA + ~8 VALU + ~8 LDS-pipe + ~15us EXPOSED LATENCY at ~2.3
// waves/SIMD (measured residency pins at ~60% of static; LDS-limit changes
// were null because 60% of a small static cap is still small).
// ROUND-11 CHANGE: raise the static cap itself. Apl (12KB) is live only for
// the first reads -> stage A THROUGH Bpl (A planes -> barrier -> Af regs ->
// barrier -> B chunk 0 + zero plane 3). LDS = Bpl 16KB + scr 4KB = 20480B ->
// 8 blocks/CU static (exactly 160KiB); CH 4->2 so grid = 2048 = exactly 8/CU.
// Everything else (fragments, min2 scr machinery, epilogues) verbatim R9.
__global__ __launch_bounds__(256) void chamfer_mfma(
        const s16x8* __restrict__ Afrag, const s16x8* __restrict__ Bfrag,
        unsigned int* __restrict__ min1, unsigned int* __restrict__ min2) {
    __shared__ s16x8 Bpl[4][256];        // 16KB (plane 3 = zeros in loop)
    __shared__ float scr[4 * 16 * 16];   // 4KB min2 wave-combine scratch

    const int bid = blockIdx.x;
    const int b   = bid >> 10;           // 1024 blocks per batch
    const int rr  = bid & 1023;
    const int ob  = rr >> 4;             // 64 owner blocks
    const int bin = rr & 15;             // 16 scan bins of 512
    const int nb    = ob * 256;
    const int mbase = bin * (CH * 256);

    const int t = threadIdx.x;
    const int w = t >> 6, l = t & 63;
    const int tl = t >> 4, c15 = t & 15;
    const s16x8 zfrag = {0, 0, 0, 0, 0, 0, 0, 0};

    const s16x8* Ab = Afrag + (size_t)(b * 3) * N_;
    const s16x8* Bb = Bfrag + (size_t)(b * 3) * M_;
    unsigned int* m1g = min1 + (size_t)b * N_;
    unsigned int* m2g = min2 + (size_t)b * M_;

    // ---- phase 1: stage A planes THROUGH Bpl; B chunk-0 loads issue now ----
    s16x8 b0 = Bb[0 * M_ + mbase + t];   // global loads in flight across
    s16x8 b1 = Bb[1 * M_ + mbase + t];   // the A staging phase
    s16x8 b2 = Bb[2 * M_ + mbase + t];
    {
        s16x8 a0 = Ab[0 * N_ + nb + t];
        s16x8 a1 = Ab[1 * N_ + nb + t];
        s16x8 a2 = Ab[2 * N_ + nb + t];
        Bpl[0][t] = a0;
        Bpl[1][t] = a1;
        Bpl[2][t] = a2;
    }
    __syncthreads();

    s16x8 Af[4];
    #pragma unroll
    for (int r = 0; r < 4; r++)
        Af[r] = (l < 48) ? Bpl[l >> 4][(4 * w + r) * 16 + (l & 15)] : zfrag;
    __syncthreads();                     // Af read complete; Bpl reusable

    // ---- phase 2: stage B chunk 0 + zero plane 3 ----
    Bpl[3][t] = zfrag;
    Bpl[0][t] = b0;
    Bpl[1][t] = b1;
    Bpl[2][t] = b2;
    __syncthreads();

    f32x4 mn1v[4];
    #pragma unroll
    for (int r = 0; r < 4; r++)
        mn1v[r] = (f32x4){3.402823466e38f, 3.402823466e38f,
                          3.402823466e38f, 3.402823466e38f};

    const f32x4 zacc = {0.f, 0.f, 0.f, 0.f};
    const s16x8* Bflat = &Bpl[0][0];
    const int boff = (l >> 4) * 256 + (l & 15);   // plane 3 for l>=48 -> zeros

    // ---- chunk loop ----
    for (int c = 0; c < CH; c++) {
        // prefetch next chunk to regs; loads land under compute
        s16x8 pb0, pb1, pb2;
        if (c + 1 < CH) {
            int src = mbase + (c + 1) * 256 + t;
            pb0 = Bb[0 * M_ + src];
            pb1 = Bb[1 * M_ + src];
            pb2 = Bb[2 * M_ + src];
        }
        // 8 tile-pairs; min1 accumulated pairwise with v_min3
        #pragma unroll 2
        for (int mp = 0; mp < 8; mp++) {
            s16x8 Bf0 = Bflat[boff + (2 * mp) * 16];
            s16x8 Bf1 = Bflat[boff + (2 * mp + 1) * 16];
            float p20 = 3.402823466e38f, p21 = 3.402823466e38f;
            #pragma unroll
            for (int r = 0; r < 4; r++) {
                f32x4 aA = __builtin_amdgcn_mfma_f32_16x16x32_bf16(Af[r], Bf0, zacc, 0, 0, 0);
                f32x4 aB = __builtin_amdgcn_mfma_f32_16x16x32_bf16(Af[r], Bf1, zacc, 0, 0, 0);
                mn1v[r].x = min3f(mn1v[r].x, aA.x, aB.x);
                mn1v[r].y = min3f(mn1v[r].y, aA.y, aB.y);
                mn1v[r].z = min3f(mn1v[r].z, aA.z, aB.z);
                mn1v[r].w = min3f(mn1v[r].w, aA.w, aB.w);
                p20 = min3f(p20, min3f(aA.x, aA.y, aA.z), aA.w);
                p21 = min3f(p21, min3f(aB.x, aB.y, aB.z), aB.w);
            }
            // cross row-group col-min (col = l&15), store wave partial
            p20 = fminf(p20, __shfl_xor(p20, 16));
            p20 = fminf(p20, __shfl_xor(p20, 32));
            p21 = fminf(p21, __shfl_xor(p21, 16));
            p21 = fminf(p21, __shfl_xor(p21, 32));
            if (l < 16) {
                scr[(w * 16 + 2 * mp) * 16 + l]     = p20;
                scr[(w * 16 + 2 * mp + 1) * 16 + l] = p21;
            }
        }
        __syncthreads();   // scr complete; all waves done reading Bpl
        // combine 4 wave partials per col -> one atomic per col (256/chunk)
        {
            float v = fminf(fminf(scr[(0 * 16 + tl) * 16 + c15],
                                  scr[(1 * 16 + tl) * 16 + c15]),
                            fminf(scr[(2 * 16 + tl) * 16 + c15],
                                  scr[(3 * 16 + tl) * 16 + c15]));
            atomicMin(&m2g[mbase + c * 256 + tl * 16 + c15], __float_as_uint(v));
        }
        // restage next chunk from the prefetched regs
        if (c + 1 < CH) {
            Bpl[0][t] = pb0;
            Bpl[1][t] = pb1;
            Bpl[2][t] = pb2;
        }
        __syncthreads();   // Bpl(c+1) ready; scr reads done before overwrite
    }

    // ---- epilogue: min1 (reduce over the 16 cols held across lanes l&15) ----
    #pragma unroll
    for (int r = 0; r < 4; r++) {
        #pragma unroll
        for (int q = 0; q < 4; q++) {
            float v = mn1v[r][q];
            v = fminf(v, __shfl_xor(v, 1));
            v = fminf(v, __shfl_xor(v, 2));
            v = fminf(v, __shfl_xor(v, 4));
            v = fminf(v, __shfl_xor(v, 8));
            if ((l & 15) == 0) {
                int row = nb + (4 * w + r) * 16 + (l >> 4) * 4 + q;
                // distances non-negative: float bits order as uint
                atomicMin(&m1g[row], __float_as_uint(v));
            }
        }
    }
}

__global__ __launch_bounds__(1024) void finalize_kernel(
        const float* __restrict__ wts,
        const float* __restrict__ min1,
        const float* __restrict__ min2,
        const float* __restrict__ wmax_part,
        float* __restrict__ out) {
    __shared__ float red[16];
    int b = blockIdx.x;
    const float* wb = wts + b * N_;
    const float* m1 = min1 + b * N_;
    const float* m2 = min2 + b * M_;

    float lmax = (threadIdx.x < 256) ? wmax_part[b * 256 + threadIdx.x]
                                     : -3.402823466e38f;
    float gmax = blk_reduce_max(lmax, red);

    float se = 0.0f, swm = 0.0f;
    for (int i = threadIdx.x; i < N_ / 4; i += blockDim.x) {
        f32x4 w4 = ((const f32x4*)wb)[i];
        f32x4 m4 = ((const f32x4*)m1)[i];
        #pragma unroll
        for (int k = 0; k < 4; k++) {
            float e = expf(w4[k] - gmax);
            se += e;
            swm += e * m4[k];
        }
    }
    float tse = blk_reduce_sum(se, red);
    float tswm = blk_reduce_sum(swm, red);

    float sm2 = 0.0f;
    for (int i = threadIdx.x; i < M_ / 4; i += blockDim.x) {
        f32x4 m4 = ((const f32x4*)m2)[i];
        sm2 += (m4.x + m4.y) + (m4.z + m4.w);
    }
    float tsm2 = blk_reduce_sum(sm2, red);

    if (threadIdx.x == 0)
        atomicAdd(out, (tswm / tse + tsm2 * (1.0f / (float)M_)) * (1.0f / (float)B_));
}

// ---------------- launch ----------------

extern "C" void kernel_launch(void* const* d_in, const int* in_sizes, int n_in,
                              void* d_out, int out_size, void* d_ws, size_t ws_size,
                              hipStream_t stream) {
    const float* p1  = (const float*)d_in[0];  // (B, N, 3)
    const float* p2  = (const float*)d_in[1];  // (B, M, 3)
    const float* wts = (const float*)d_in[2];  // (B, N)
    float* out = (float*)d_out;

    // workspace layout (16B-aligned sections):
    //   min1: B*N u32 (128KB) | min2: B*M u32 (64KB) | wmax: 512 f32 (pad 4KB)
    //   Afrag: B*3*N s16x8 (1.5MB) | Bfrag: B*3*M s16x8 (768KB)
    unsigned int* min1 = (unsigned int*)d_ws;            // B*N
    unsigned int* min2 = min1 + B_ * N_;                 // B*M
    float* wmax_part = (float*)(min2 + B_ * M_);         // 512 floats
    char* frag_base = (char*)d_ws + 196608 + 4096;       // 16B aligned
    s16x8* Afrag = (s16x8*)frag_base;                    // B*3*N quads
    s16x8* Bfrag = Afrag + B_ * 3 * N_;                  // B*3*M quads

    init_ws<<<dim3((B_ * N_) / 256), dim3(256), 0, stream>>>(
        wts, p1, p2, min1, min2, wmax_part, Afrag, Bfrag, out);
    // 2 batches * 64 owner-blocks * 16 scan-bins = 2048 blocks (8/CU)
    chamfer_mfma<<<dim3(B_ * 64 * (M_ / (CH * 256))), dim3(256), 0, stream>>>(
        Afrag, Bfrag, min1, min2);
    finalize_kernel<<<dim3(B_), dim3(1024), 0, stream>>>(
        wts, (const float*)min1, (const float*)min2, wmax_part, out);
}

// Round 12
// 46.707 us; speedup vs baseline: 1.1633x; 1.0299x over previous
//
#include <hip/hip_runtime.h>

#define B_ 2
#define N_ 16384
#define M_ 8192
#define CH 2                      // scan chunks per block (2*256 = 512 cols)

typedef float f32x4 __attribute__((ext_vector_type(4)));
typedef float f32x16 __attribute__((ext_vector_type(16)));
typedef short s16x8 __attribute__((ext_vector_type(8)));

__device__ inline float min3f(float a, float b, float c) {
    float d;
    asm("v_min3_f32 %0, %1, %2, %3" : "=v"(d) : "v"(a), "v"(b), "v"(c));
    return d;
}

// RNE f32 -> bf16 (bits)
__device__ inline unsigned short f2bf(float f) {
    unsigned int u = __float_as_uint(f);
    u += 0x7FFFu + ((u >> 16) & 1u);
    return (unsigned short)(u >> 16);
}
__device__ inline float bf2f(unsigned short h) {
    return __uint_as_float(((unsigned int)h) << 16);
}
// 2-way bf16 split: v ~= h + m, residual ~2^-18 rel
__device__ inline void split2(float v, unsigned short& hb, unsigned short& mb) {
    hb = f2bf(v);
    mb = f2bf(v - bf2f(hb));
}

#define ONE_BF ((short)0x3F80)

// K=16 slot map (s = slot index, identical placement function for A and B —
// layout-robust: whatever the HW (lane,elem)->k bijection is, A and B share
// it, and the k-sum is permutation-invariant; same argument as the verified
// 16x16x32 kernel):
//  s0-2:  uh_d * yh_d   s3-5:  uh_d * ym_d   s6-8:  um_d * yh_d
//  s9-11: um_d * ym_d   s12,13: sq1{h,m}*1   s14,15: 1*sq2{h,m}
// Sum = (uh+um)(yh+ym) per dim + sq1 + sq2 = |x-y|^2 + O(2^-18)
__device__ inline void buildA2(float x0, float x1, float x2,
                               s16x8& q0, s16x8& q1) {
    float sq = fmaf(x0, x0, fmaf(x1, x1, x2 * x2));
    unsigned short uh[3], um[3], sh, sm;
    split2(-2.f * x0, uh[0], um[0]);
    split2(-2.f * x1, uh[1], um[1]);
    split2(-2.f * x2, uh[2], um[2]);
    split2(sq, sh, sm);
    q0 = (s16x8){(short)uh[0], (short)uh[1], (short)uh[2], (short)uh[0],
                 (short)uh[1], (short)uh[2], (short)um[0], (short)um[1]};
    q1 = (s16x8){(short)um[2], (short)um[0], (short)um[1], (short)um[2],
                 (short)sh, (short)sm, ONE_BF, ONE_BF};
}
__device__ inline void buildB2(float y0, float y1, float y2,
                               s16x8& q0, s16x8& q1) {
    float sq = fmaf(y0, y0, fmaf(y1, y1, y2 * y2));
    unsigned short yh[3], ym[3], sh, sm;
    split2(y0, yh[0], ym[0]);
    split2(y1, yh[1], ym[1]);
    split2(y2, yh[2], ym[2]);
    split2(sq, sh, sm);
    q0 = (s16x8){(short)yh[0], (short)yh[1], (short)yh[2], (short)ym[0],
                 (short)ym[1], (short)ym[2], (short)yh[0], (short)yh[1]};
    q1 = (s16x8){(short)yh[2], (short)ym[0], (short)ym[1], (short)ym[2],
                 ONE_BF, ONE_BF, (short)sh, (short)sm};
}

// ---------------- reductions ----------------

__device__ inline float blk_reduce_max(float v, float* red) {
    #pragma unroll
    for (int off = 32; off; off >>= 1) v = fmaxf(v, __shfl_xor(v, off));
    int wid = threadIdx.x >> 6;
    int lane = threadIdx.x & 63;
    int nw = blockDim.x >> 6;
    if (lane == 0) red[wid] = v;
    __syncthreads();
    if (wid == 0) {
        v = (lane < nw) ? red[lane] : -3.402823466e38f;
        #pragma unroll
        for (int off = 32; off; off >>= 1) v = fmaxf(v, __shfl_xor(v, off));
        if (lane == 0) red[0] = v;
    }
    __syncthreads();
    v = red[0];
    __syncthreads();
    return v;
}

__device__ inline float blk_reduce_sum(float v, float* red) {
    #pragma unroll
    for (int off = 32; off; off >>= 1) v += __shfl_xor(v, off);
    int wid = threadIdx.x >> 6;
    int lane = threadIdx.x & 63;
    int nw = blockDim.x >> 6;
    if (lane == 0) red[wid] = v;
    __syncthreads();
    if (wid == 0) {
        v = (lane < nw) ? red[lane] : 0.0f;
        #pragma unroll
        for (int off = 32; off; off >>= 1) v += __shfl_xor(v, off);
        if (lane == 0) red[0] = v;
    }
    __syncthreads();
    v = red[0];
    __syncthreads();
    return v;
}

// ---------------- kernels ----------------

// grid 192 blocks (spread over 192 CUs; old 128-block version left half the
// chip idle for ~5us). Threads j<B*N handle p1 (min1 init + wmax + A-frag);
// j>=B*N handle p2 (min2 init + B-frag). One fragment build per thread.
__global__ __launch_bounds__(256) void init_ws(const float* __restrict__ wts,
                                               const float* __restrict__ p1,
                                               const float* __restrict__ p2,
                                               unsigned int* min1, unsigned int* min2,
                                               float* __restrict__ wmax_part,
                                               s16x8* __restrict__ Afrag,
                                               s16x8* __restrict__ Bfrag,
                                               float* out) {
    int j = blockIdx.x * 256 + threadIdx.x;   // [0, B*N + B*M)
    if (j == 0) out[0] = 0.0f;
    if (j < B_ * N_) {
        min1[j] = 0x7F7FFFFFu;                // FLT_MAX bits
        float v = wts[j];
        #pragma unroll
        for (int off = 32; off; off >>= 1) v = fmaxf(v, __shfl_xor(v, off));
        if ((j & 63) == 0) wmax_part[j >> 6] = v;   // 512 wave partials

        int b = j >> 14, n = j & (N_ - 1);
        const float* px = p1 + (size_t)j * 3;
        s16x8 q0, q1;
        buildA2(px[0], px[1], px[2], q0, q1);
        Afrag[((size_t)b * 2 + 0) * N_ + n] = q0;
        Afrag[((size_t)b * 2 + 1) * N_ + n] = q1;
    } else {
        int k = j - B_ * N_;                  // [0, B*M)
        min2[k] = 0x7F7FFFFFu;
        int b = k >> 13, m = k & (M_ - 1);
        const float* py = p2 + (size_t)k * 3;
        s16x8 q0, q1;
        buildB2(py[0], py[1], py[2], q0, q1);
        Bfrag[((size_t)b * 2 + 0) * M_ + m] = q0;
        Bfrag[((size_t)b * 2 + 1) * M_ + m] = q1;
    }
}

// ROUND-12: 32x32x16 MFMA + 2-way split (K=16 exactly: 12 product slots +
// 2 sq1 + 2 sq2). One MFMA = 1024 distances (4x the 16x16x32 tile), K halved
// -> MFMA cycles/distance halve; per 2048 distances the in-loop stream drops
// from {8 MFMA + 8 ds_read + 128 VALU + 16 shfl} to {2 MFMA + 2 ds_read +
// ~48 VALU + 1 shfl}. C/D map (HW-verified m74/m101): col=lane&31,
// row=(reg&3)+8*(reg>>2)+4*(lane>>5). Block: 4 waves x 64 owner rows = 256
// owners; scan CH=2 chunks x 256 cols; grid 2048. LDS: Bsh 8KB + scr 4KB.
// Per-distance error ~1e-4 (2-way split), but the checked output is the
// final averaged scalar -> expected absmax ~1e-5 (threshold 7.8e-4).
__global__ __launch_bounds__(256) void chamfer_mfma(
        const s16x8* __restrict__ Afrag, const s16x8* __restrict__ Bfrag,
        unsigned int* __restrict__ min1, unsigned int* __restrict__ min2) {
    __shared__ s16x8 Bsh[2][256];        // [k-half][col] = 8KB
    __shared__ float scr[4][8][32];      // wave x tile x col = 4KB

    const int bid = blockIdx.x;
    const int b   = bid >> 10;           // 1024 blocks per batch
    const int rr  = bid & 1023;
    const int ob  = rr >> 4;             // 64 owner blocks (256 rows each)
    const int bin = rr & 15;             // 16 scan bins of 512
    const int nb    = ob * 256;
    const int mbase = bin * (CH * 256);

    const int t = threadIdx.x;
    const int w = t >> 6, l = t & 63;
    const int lc = l & 31, lh = l >> 5;

    const s16x8* Ab = Afrag + (size_t)(b * 2) * N_;
    const s16x8* Bb = Bfrag + (size_t)(b * 2) * M_;
    unsigned int* m1g = min1 + (size_t)b * N_;
    unsigned int* m2g = min2 + (size_t)b * M_;

    // ---- stage A through Bsh (B chunk-0 loads issue first, in flight) ----
    s16x8 b0 = Bb[0 * M_ + mbase + t];
    s16x8 b1 = Bb[1 * M_ + mbase + t];
    {
        s16x8 a0 = Ab[0 * N_ + nb + t];
        s16x8 a1 = Ab[1 * N_ + nb + t];
        Bsh[0][t] = a0;
        Bsh[1][t] = a1;
    }
    __syncthreads();
    s16x8 Af0 = Bsh[lh][w * 64 + lc];        // row-tile r0 = nb + w*64
    s16x8 Af1 = Bsh[lh][w * 64 + 32 + lc];   // row-tile r1 = nb + w*64 + 32
    __syncthreads();
    Bsh[0][t] = b0;
    Bsh[1][t] = b1;
    __syncthreads();

    f32x16 mn1a, mn1b;
    #pragma unroll
    for (int i = 0; i < 16; i++) { mn1a[i] = 3.402823466e38f; mn1b[i] = 3.402823466e38f; }
    f32x16 zacc;
    #pragma unroll
    for (int i = 0; i < 16; i++) zacc[i] = 0.f;

    // ---- chunk loop ----
    for (int c = 0; c < CH; c++) {
        s16x8 pb0, pb1;
        if (c + 1 < CH) {
            int src = mbase + (c + 1) * 256 + t;
            pb0 = Bb[0 * M_ + src];
            pb1 = Bb[1 * M_ + src];
        }
        #pragma unroll 2
        for (int mt = 0; mt < 8; mt++) {
            s16x8 Bf = Bsh[lh][mt * 32 + lc];
            f32x16 aA = __builtin_amdgcn_mfma_f32_32x32x16_bf16(Af0, Bf, zacc, 0, 0, 0);
            f32x16 aB = __builtin_amdgcn_mfma_f32_32x32x16_bf16(Af1, Bf, zacc, 0, 0, 0);
            // min1 folds (16 rows per acc, same col per lane)
            #pragma unroll
            for (int i = 0; i < 16; i++) {
                mn1a[i] = fminf(mn1a[i], aA[i]);
                mn1b[i] = fminf(mn1b[i], aB[i]);
            }
            // min2: fold the 32 in-lane values (this lane's col, 32 rows)
            float f0 = min3f(aA[0], aA[1], aA[2]);
            float f1 = min3f(aA[3], aA[4], aA[5]);
            float f2 = min3f(aA[6], aA[7], aA[8]);
            float f3 = min3f(aA[9], aA[10], aA[11]);
            float f4 = min3f(aA[12], aA[13], aA[14]);
            float f5 = min3f(aA[15], aB[0], aB[1]);
            float f6 = min3f(aB[2], aB[3], aB[4]);
            float f7 = min3f(aB[5], aB[6], aB[7]);
            float f8 = min3f(aB[8], aB[9], aB[10]);
            float f9 = min3f(aB[11], aB[12], aB[13]);
            float g0 = min3f(f0, f1, f2);
            float g1 = min3f(f3, f4, f5);
            float g2 = min3f(f6, f7, f8);
            float g3 = min3f(f9, aB[14], aB[15]);
            float m2 = fminf(fminf(g0, g1), fminf(g2, g3));
            // merge the other row-half (lane ^32 holds rows +4, same col)
            m2 = fminf(m2, __shfl_xor(m2, 32));
            if (l < 32) scr[w][mt][l] = m2;
        }
        __syncthreads();   // scr complete; all waves done reading Bsh
        // combine 4 wave partials per col -> one atomic per col (256/chunk)
        {
            int mt2 = t >> 5, cc = t & 31;
            float v = fminf(fminf(scr[0][mt2][cc], scr[1][mt2][cc]),
                            fminf(scr[2][mt2][cc], scr[3][mt2][cc]));
            atomicMin(&m2g[mbase + c * 256 + mt2 * 32 + cc], __float_as_uint(v));
        }
        if (c + 1 < CH) {
            Bsh[0][t] = pb0;
            Bsh[1][t] = pb1;
        }
        __syncthreads();
    }

    // ---- epilogue: min1 — reduce each row-reg across the 32 cols (l&31) ----
    #pragma unroll
    for (int i = 0; i < 16; i++) {
        float v = mn1a[i];
        v = fminf(v, __shfl_xor(v, 1));
        v = fminf(v, __shfl_xor(v, 2));
        v = fminf(v, __shfl_xor(v, 4));
        v = fminf(v, __shfl_xor(v, 8));
        v = fminf(v, __shfl_xor(v, 16));
        float u = mn1b[i];
        u = fminf(u, __shfl_xor(u, 1));
        u = fminf(u, __shfl_xor(u, 2));
        u = fminf(u, __shfl_xor(u, 4));
        u = fminf(u, __shfl_xor(u, 8));
        u = fminf(u, __shfl_xor(u, 16));
        if (lc == 0) {
            int row = nb + w * 64 + (i & 3) + 8 * (i >> 2) + 4 * lh;
            atomicMin(&m1g[row], __float_as_uint(v));
            atomicMin(&m1g[row + 32], __float_as_uint(u));
        }
    }
}

__global__ __launch_bounds__(1024) void finalize_kernel(
        const float* __restrict__ wts,
        const float* __restrict__ min1,
        const float* __restrict__ min2,
        const float* __restrict__ wmax_part,
        float* __restrict__ out) {
    __shared__ float red[16];
    int b = blockIdx.x;
    const float* wb = wts + b * N_;
    const float* m1 = min1 + b * N_;
    const float* m2 = min2 + b * M_;

    float lmax = (threadIdx.x < 256) ? wmax_part[b * 256 + threadIdx.x]
                                     : -3.402823466e38f;
    float gmax = blk_reduce_max(lmax, red);

    float se = 0.0f, swm = 0.0f;
    for (int i = threadIdx.x; i < N_ / 4; i += blockDim.x) {
        f32x4 w4 = ((const f32x4*)wb)[i];
        f32x4 m4 = ((const f32x4*)m1)[i];
        #pragma unroll
        for (int k = 0; k < 4; k++) {
            float e = expf(w4[k] - gmax);
            se += e;
            swm += e * m4[k];
        }
    }
    float tse = blk_reduce_sum(se, red);
    float tswm = blk_reduce_sum(swm, red);

    float sm2 = 0.0f;
    for (int i = threadIdx.x; i < M_ / 4; i += blockDim.x) {
        f32x4 m4 = ((const f32x4*)m2)[i];
        sm2 += (m4.x + m4.y) + (m4.z + m4.w);
    }
    float tsm2 = blk_reduce_sum(sm2, red);

    if (threadIdx.x == 0)
        atomicAdd(out, (tswm / tse + tsm2 * (1.0f / (float)M_)) * (1.0f / (float)B_));
}

// ---------------- launch ----------------

extern "C" void kernel_launch(void* const* d_in, const int* in_sizes, int n_in,
                              void* d_out, int out_size, void* d_ws, size_t ws_size,
                              hipStream_t stream) {
    const float* p1  = (const float*)d_in[0];  // (B, N, 3)
    const float* p2  = (const float*)d_in[1];  // (B, M, 3)
    const float* wts = (const float*)d_in[2];  // (B, N)
    float* out = (float*)d_out;

    // workspace: min1 (128KB) | min2 (64KB) | wmax (pad 4KB) |
    //            Afrag B*2*N quads (1MB) | Bfrag B*2*M quads (0.5MB)
    unsigned int* min1 = (unsigned int*)d_ws;            // B*N
    unsigned int* min2 = min1 + B_ * N_;                 // B*M
    float* wmax_part = (float*)(min2 + B_ * M_);         // 512 floats
    char* frag_base = (char*)d_ws + 196608 + 4096;       // 16B aligned
    s16x8* Afrag = (s16x8*)frag_base;                    // B*2*N quads
    s16x8* Bfrag = Afrag + B_ * 2 * N_;                  // B*2*M quads

    // 192 blocks = (B*N + B*M) / 256
    init_ws<<<dim3((B_ * N_ + B_ * M_) / 256), dim3(256), 0, stream>>>(
        wts, p1, p2, min1, min2, wmax_part, Afrag, Bfrag, out);
    // 2 batches * 64 owner-blocks * 16 scan-bins = 2048 blocks
    chamfer_mfma<<<dim3(B_ * (N_ / 256) * (M_ / (CH * 256))), dim3(256), 0, stream>>>(
        Afrag, Bfrag, min1, min2);
    finalize_kernel<<<dim3(B_), dim3(1024), 0, stream>>>(
        wts, (const float*)min1, (const float*)min2, wmax_part, out);
}